// Round 10
// baseline (134.792 us; speedup 1.0000x reference)
//
#include <hip/hip_runtime.h>
#include <stdint.h>

// LmHead: RMSNorm(8x4096) -> logits = h @ W^T (W: 32000x4096 f32) -> argmax per row.
// Memory-bound: W is 524 MB -> HBM read stream, floor ~81us @ fill-calibrated 6.5.
// R4 (126us, BEST): reg h+W dbuf ping-pong, counted vmcnt, nt W, VT=4.
//   Kernel B ~122us = 4.3 TB/s; overhead outside B is only ~4us (R7 profile).
// R9 (134us): plain W on R4 shape -> L3 thrashes cyclically (no replay reuse),
//   plain costs ~8us in pollution. nt wins WHEN there is no reuse to capture.
// R10: create the reuse. Twin waves (same block) share one VT=8 vocab group,
//   each owning 4 batch rows: identical W addresses ~concurrently -> L2/MSHR
//   serves the twin (HBM W stays 524MB), h traffic per wave HALVES (4KB vs
//   8KB per 8KB W). Plain W loads (nt would defeat twin reuse). R4 pipeline.

#define D 4096
#define BATCH 8
#define VOCAB 32000
#define VT 8                 // vocab rows per group (twin waves share a group)
#define NBLK 2000            // 2 groups/block * 2000 = 4000 groups = 32000 rows
#define EPS 1e-6f

typedef unsigned long long u64;
typedef float f32x4 __attribute__((ext_vector_type(4)));

// ---------------- Kernel A: RMSNorm -> h in workspace ----------------
__global__ __launch_bounds__(256) void rmsnorm_k(const float* __restrict__ x,
                                                 const float* __restrict__ g,
                                                 float* __restrict__ h) {
    const int b = blockIdx.x;
    const int t = threadIdx.x;
    const int wave = t >> 6, lane = t & 63;
    const float* xr = x + b * D;

    f32x4 xv[4];
    float s = 0.f;
#pragma unroll
    for (int i = 0; i < 4; ++i) {
        xv[i] = *(const f32x4*)(xr + i * 1024 + t * 4);
        s += xv[i].x * xv[i].x + xv[i].y * xv[i].y + xv[i].z * xv[i].z + xv[i].w * xv[i].w;
    }
#pragma unroll
    for (int m = 1; m < 64; m <<= 1) s += __shfl_xor(s, m, 64);

    __shared__ float wsum[4];
    if (lane == 0) wsum[wave] = s;
    __syncthreads();
    const float tot = wsum[0] + wsum[1] + wsum[2] + wsum[3];
    const float rs = rsqrtf(tot * (1.f / (float)D) + EPS);

#pragma unroll
    for (int i = 0; i < 4; ++i) {
        const int d = i * 1024 + t * 4;
        const f32x4 gv = *(const f32x4*)(g + d);
        f32x4 o;
        o.x = xv[i].x * rs * gv.x;
        o.y = xv[i].y * rs * gv.y;
        o.z = xv[i].z * rs * gv.z;
        o.w = xv[i].w * rs * gv.w;
        *(f32x4*)(h + b * D + d) = o;
    }
}

// ---- Kernel B: twin-wave batch-split GEMV, R4 ping-pong, packed argmax ----
// wave w: group = blockIdx*2 + (w>>1); batch half = w&1 (rows half*4..half*4+3)
__global__ __launch_bounds__(256) void gemv_argmax_k(const float* __restrict__ W,
                                                     const float* __restrict__ h,
                                                     u64* __restrict__ partial) {
    const int lane = threadIdx.x & 63;
    const int wave = threadIdx.x >> 6;
    const int grp = blockIdx.x * 2 + (wave >> 1);   // [0, 4000)
    const int half = wave & 1;                       // batch rows half*4 ..
    const int v0 = grp * VT;
    const float* Wb = W + (size_t)v0 * D;
    const float* hb = h + (size_t)(half * 4) * D;
    const int dl = lane * 4;

    float acc[32];                                   // [b_loc 0..3][vi 0..7]
#pragma unroll
    for (int i = 0; i < 32; ++i) acc[i] = 0.f;

    f32x4 wA[VT], wB[VT];      // W double-buffer (PLAIN: twin-wave L2 reuse)
    f32x4 hA[4], hB[4];        // h double-buffer (4 batch rows, L2-hot)

#define LOADH(HB, c)                                                           \
    {                                                                          \
        const int _d = (c) * 256 + dl;                                         \
        _Pragma("unroll")                                                      \
        for (int b = 0; b < 4; ++b)                                            \
            HB[b] = *(const f32x4*)(hb + b * D + _d);                          \
    }

#define LOADW(BUF, c)                                                          \
    {                                                                          \
        const int _d = (c) * 256 + dl;                                         \
        _Pragma("unroll")                                                      \
        for (int vi = 0; vi < VT; ++vi)                                        \
            BUF[vi] = *(const f32x4*)(Wb + vi * D + _d);                       \
    }

#define COMPUTE(HB, WBUF)                                                      \
    {                                                                          \
        _Pragma("unroll")                                                      \
        for (int b = 0; b < 4; ++b) {                                          \
            _Pragma("unroll")                                                  \
            for (int vi = 0; vi < VT; ++vi)                                    \
                acc[b * VT + vi] += WBUF[vi].x * HB[b].x + WBUF[vi].y * HB[b].y + \
                                    WBUF[vi].z * HB[b].z + WBUF[vi].w * HB[b].w;  \
        }                                                                      \
    }

    // prologue: chunk 0 in A  (issue order = use order; h before W)
    LOADH(hA, 0)
    LOADW(wA, 0)
    // steady state: issue next chunk's 12 loads, then compute current (oldest)
#pragma unroll 1
    for (int c = 0; c <= 12; c += 2) {
        LOADH(hB, c + 1)
        LOADW(wB, c + 1)
        COMPUTE(hA, wA)        // counted vmcnt -- queue never drains
        LOADH(hA, c + 2)       // c+2 <= 14
        LOADW(wA, c + 2)
        COMPUTE(hB, wB)
    }
    LOADH(hB, 15)
    LOADW(wB, 15)
    COMPUTE(hA, wA)
    COMPUTE(hB, wB)
#undef LOADH
#undef LOADW
#undef COMPUTE

    // Butterfly: 32 partials across 64 lanes -> lane l holds total for
    // j = l&31 (b_loc = j>>3, vi = j&7). All indices compile-time.
#pragma unroll
    for (int s = 0; s < 5; ++s) {
        const int m = 1 << s;
        const bool bit = (lane & m) != 0;
#pragma unroll
        for (int u = 0; u < (32 >> (s + 1)); ++u) {
            const float a = acc[2 * u];
            const float c2 = acc[2 * u + 1];
            const float keep = bit ? c2 : a;
            const float send = bit ? a : c2;
            acc[u] = keep + __shfl_xor(send, m, 64);
        }
    }
    const float logit = acc[0] + __shfl_xor(acc[0], 32, 64);  // fold dup halves

    const int vidx = v0 + (lane & 7);
    const uint32_t fb = __float_as_uint(logit);
    const uint32_t key = (fb & 0x80000000u) ? ~fb : (fb | 0x80000000u);
    u64 best = ((u64)key << 32) | (uint32_t)(~(uint32_t)vidx);

    // merge across vi (bits 0,1,2); bit-5 halves are duplicates after fold
#pragma unroll
    for (int m = 1; m <= 4; m <<= 1) {
        const u64 o = __shfl_xor(best, m, 64);
        if (o > best) best = o;
    }
    {
        const u64 o = __shfl_xor(best, 32, 64);
        if (o > best) best = o;
    }

    // lb[wave][b_loc]: wave covers batch rows half*4 + (0..3)
    __shared__ u64 lb[4][4];
    if (lane < 32 && (lane & 7) == 0) lb[wave][lane >> 3] = best;
    __syncthreads();
    if (threadIdx.x < 8) {
        const int b = threadIdx.x;
        const int hf = b >> 2, bl = b & 3;
        const u64 m0 = lb[hf][bl];       // group 0, this batch half
        const u64 m1 = lb[2 + hf][bl];   // group 1, this batch half
        partial[(size_t)blockIdx.x * 8 + b] = m0 > m1 ? m0 : m1;
    }
}

// ---------------- Kernel C: final argmax over block partials ----------------
__global__ __launch_bounds__(512) void finalize_k(const u64* __restrict__ partial,
                                                  int* __restrict__ out, int nblk) {
    const int b = threadIdx.x >> 6;   // one wave per batch row
    const int lane = threadIdx.x & 63;
    u64 best = 0ull;
    for (int p = lane; p < nblk; p += 64) {
        const u64 x = partial[(size_t)p * 8 + b];
        if (x > best) best = x;
    }
#pragma unroll
    for (int m = 1; m < 64; m <<= 1) {
        const u64 o = __shfl_xor(best, m, 64);
        if (o > best) best = o;
    }
    if (lane == 0) out[b] = (int)(~(uint32_t)best);
}

extern "C" void kernel_launch(void* const* d_in, const int* in_sizes, int n_in,
                              void* d_out, int out_size, void* d_ws, size_t ws_size,
                              hipStream_t stream) {
    const float* x = (const float*)d_in[0]; // hidden_states [8,4096]
    const float* g = (const float*)d_in[1]; // norm_weight [4096]
    const float* W = (const float*)d_in[2]; // lm_head_weight [32000,4096]
    int* out = (int*)d_out;                 // [8] int32 token ids

    float* h = (float*)d_ws;                                        // 128 KB
    u64* partial = (u64*)((char*)d_ws + BATCH * D * sizeof(float)); // 2000*8*8B

    rmsnorm_k<<<BATCH, 256, 0, stream>>>(x, g, h);
    gemv_argmax_k<<<NBLK, 256, 0, stream>>>(W, h, partial);
    finalize_k<<<1, 512, 0, stream>>>(partial, out, NBLK);
}